// Round 8
// baseline (18840.019 us; speedup 1.0000x reference)
//
#include <hip/hip_runtime.h>
#include <cstddef>
#include <cstdint>

#define T_LEN 4096
#define FDIM  1024
#define H2DIM 1024
#define GDIM  4096   // 4*H2

#define NEGV (-10000.0f)
#define START_TAG 2
#define STOP_TAG 3

// ---- workspace layout (bytes) ----
#define XP_OFF      ((size_t)0)
#define XP_BYTES    ((size_t)2 * T_LEN * GDIM * 4)          // 134,217,728
#define HIST_OFF    (XP_OFF + XP_BYTES)
#define HIST_BYTES  ((size_t)T_LEN * 2048 * 4)              // 33,554,432
#define FEATS_OFF   (HIST_OFF + HIST_BYTES)
#define FEATS_BYTES ((size_t)T_LEN * 4 * 4)
#define SLOTS_OFF   (FEATS_OFF + FEATS_BYTES)
#define SLOTS_BYTES ((size_t)2 * 2 * 1024 * 8)              // parity x dir x unit, u64
#define WS_NEED     (SLOTS_OFF + SLOTS_BYTES)

__device__ __forceinline__ float sigm(float x) { return 1.0f / (1.0f + expf(-x)); }

// ============================================================================
// Kernel 1: xp[dir][s][j] = dot(x[row(s)], w_ih_dir[j]) + b_ih[j] + b_hh[j]
// dir=0: row=s ; dir=1: row = 4095-s (backward scan order).
// 128x128 tile, BK=32, 256 threads, 8x8 microtile. fp32 (no fp32 MFMA).
// ============================================================================
__global__ __launch_bounds__(256)
void xp_gemm(const float* __restrict__ x,
             const float* __restrict__ w_f, const float* __restrict__ w_b,
             const float* __restrict__ bi_f, const float* __restrict__ bh_f,
             const float* __restrict__ bi_b, const float* __restrict__ bh_b,
             float* __restrict__ xp)
{
    const int tid = threadIdx.x;
    const int dir = blockIdx.z;
    const int j0  = blockIdx.x * 128;
    const int t0  = blockIdx.y * 128;
    const float* __restrict__ w  = dir ? w_b  : w_f;
    const float* __restrict__ bi = dir ? bi_b : bi_f;
    const float* __restrict__ bh = dir ? bh_b : bh_f;

    __shared__ float As[32][133];   // [k][m], padded
    __shared__ float Bs[32][133];   // [k][n]

    const int tm0 = (tid & 15) * 8;
    const int tn0 = (tid >> 4) * 8;

    float acc[8][8];
    #pragma unroll
    for (int i = 0; i < 8; ++i)
        #pragma unroll
        for (int j = 0; j < 8; ++j) acc[i][j] = 0.f;

    const int lrow = tid >> 3;        // 0..31
    const int lkq  = (tid & 7) * 4;   // 0..28

    for (int kb = 0; kb < FDIM; kb += 32) {
        #pragma unroll
        for (int hh = 0; hh < 4; ++hh) {
            const int r  = lrow + hh * 32;            // 0..127
            const int tg = t0 + r;
            const int sr = dir ? (T_LEN - 1 - tg) : tg;
            const float4 av = *(const float4*)&x[(size_t)sr * FDIM + kb + lkq];
            As[lkq+0][r] = av.x; As[lkq+1][r] = av.y; As[lkq+2][r] = av.z; As[lkq+3][r] = av.w;
            const float4 bv = *(const float4*)&w[(size_t)(j0 + r) * FDIM + kb + lkq];
            Bs[lkq+0][r] = bv.x; Bs[lkq+1][r] = bv.y; Bs[lkq+2][r] = bv.z; Bs[lkq+3][r] = bv.w;
        }
        __syncthreads();
        #pragma unroll
        for (int k = 0; k < 32; ++k) {
            const float4 a0 = *(const float4*)&As[k][tm0];
            const float4 a1 = *(const float4*)&As[k][tm0 + 4];
            const float4 b0 = *(const float4*)&Bs[k][tn0];
            const float4 b1 = *(const float4*)&Bs[k][tn0 + 4];
            const float av[8] = {a0.x,a0.y,a0.z,a0.w,a1.x,a1.y,a1.z,a1.w};
            const float bv[8] = {b0.x,b0.y,b0.z,b0.w,b1.x,b1.y,b1.z,b1.w};
            #pragma unroll
            for (int i = 0; i < 8; ++i)
                #pragma unroll
                for (int j = 0; j < 8; ++j) acc[i][j] += av[i] * bv[j];
        }
        __syncthreads();
    }

    float bias[8];
    #pragma unroll
    for (int j = 0; j < 8; ++j) { const int col = j0 + tn0 + j; bias[j] = bi[col] + bh[col]; }

    float* __restrict__ xpd = xp + (size_t)dir * T_LEN * GDIM;
    #pragma unroll
    for (int i = 0; i < 8; ++i) {
        const int tr = t0 + tm0 + i;
        float4 o0, o1;
        o0.x = acc[i][0] + bias[0]; o0.y = acc[i][1] + bias[1];
        o0.z = acc[i][2] + bias[2]; o0.w = acc[i][3] + bias[3];
        o1.x = acc[i][4] + bias[4]; o1.y = acc[i][5] + bias[5];
        o1.z = acc[i][6] + bias[6]; o1.w = acc[i][7] + bias[7];
        *(float4*)&xpd[(size_t)tr * GDIM + j0 + tn0]     = o0;
        *(float4*)&xpd[(size_t)tr * GDIM + j0 + tn0 + 4] = o1;
    }
}

// ============================================================================
// Kernel 2: cooperative persistent bidirectional LSTM scan, v7.
// Identical to v6 (R7) except ONE change: s_sleep(1) restored in the poll
// loop. Evidence: R2 (sleep) 13.28ms vs R7 (no sleep, same memory engine)
// 16.62ms, FETCH +240MB -- unthrottled spin traffic congests the LLC/fabric
// and delays the producers' slot stores, raising the max-over-256-blocks
// discovery latency that sets the step period.
// ============================================================================
#define DOT4(a,b) ((a).x*(b).x + (a).y*(b).y + (a).z*(b).z + (a).w*(b).w)

__global__ __launch_bounds__(256, 1)
void lstm_scan(const float* __restrict__ xp,
               const float* __restrict__ h0,
               const float* __restrict__ c0,
               const float* __restrict__ whh_f,
               const float* __restrict__ whh_b,
               float* __restrict__ hist,
               unsigned long long* __restrict__ slots)
{
    __shared__ float wsl[32][1024];   // 131,072 B
    __shared__ float hbuf[2][1024];   //   8,192 B, parity double-buffer

    const int tid = threadIdx.x;
    const int b   = blockIdx.x;
    const int dir = b >> 7;
    const int u0  = (b & 127) * 8;
    const int rg  = tid >> 5;   // unit within block: 0..7
    const int kc  = tid & 31;   // k-chunk: float4 at s*128 + kc*4
    const int lrb = rg * 4;     // this thread's 4 weight rows (gates of unit)
    const int unit = u0 + rg;

    const float* __restrict__ whh = dir ? whh_b : whh_f;
    const size_t xpbase = (size_t)dir * T_LEN * GDIM;

    // ---- stage w_hh: LDS row r = rg*4+g  <->  global row (g<<10)+u0+rg ----
    for (int r = 0; r < 32; ++r) {
        const int grow = ((r & 3) << 10) + u0 + (r >> 2);
        *(float4*)&wsl[r][tid * 4] = *(const float4*)&whh[(size_t)grow * H2DIM + tid * 4];
    }

    // ---- init h, c, xp(t=0), xp(t=1) ----
    *(float4*)&hbuf[0][tid * 4] = *(const float4*)&h0[dir * H2DIM + tid * 4];
    float creg = 0.f;
    float xpc0 = 0.f, xpc1 = 0.f, xpc2 = 0.f, xpc3 = 0.f;   // step t
    float xpn0 = 0.f, xpn1 = 0.f, xpn2 = 0.f, xpn3 = 0.f;   // step t+1
    if (kc == 0) {
        creg = c0[dir * H2DIM + unit];
        xpc0 = xp[xpbase + unit];
        xpc1 = xp[xpbase + unit + 1024];
        xpc2 = xp[xpbase + unit + 2048];
        xpc3 = xp[xpbase + unit + 3072];
        xpn0 = xp[xpbase + GDIM + unit];
        xpn1 = xp[xpbase + GDIM + unit + 1024];
        xpn2 = xp[xpbase + GDIM + unit + 2048];
        xpn3 = xp[xpbase + GDIM + unit + 3072];
    }
    __syncthreads();

    int budget = 2000000;   // hang-proof poll budget (sweeps, shared over steps)

    for (int t = 0; t < T_LEN; ++t) {
        const float* __restrict__ hb = hbuf[t & 1];

        // depth-2 prefetch: issue xp(t+2) now, consumed two steps later
        float xq0 = 0.f, xq1 = 0.f, xq2 = 0.f, xq3 = 0.f;
        const int tq = (t + 2 < T_LEN) ? (t + 2) : t;
        if (kc == 0) {
            const size_t base = xpbase + (size_t)tq * GDIM + unit;
            xq0 = xp[base];
            xq1 = xp[base + 1024];
            xq2 = xp[base + 2048];
            xq3 = xp[base + 3072];
        }

        // ---- partial dots: 4 gate rows x 32 k-elems (LDS, conflict-free) ----
        float p0 = 0.f, p1 = 0.f, p2 = 0.f, p3 = 0.f;
        #pragma unroll
        for (int s = 0; s < 8; ++s) {
            const int ko = s * 128 + kc * 4;
            const float4 hv = *(const float4*)&hb[ko];
            const float4 w0 = *(const float4*)&wsl[lrb + 0][ko];
            const float4 w1 = *(const float4*)&wsl[lrb + 1][ko];
            const float4 w2 = *(const float4*)&wsl[lrb + 2][ko];
            const float4 w3 = *(const float4*)&wsl[lrb + 3][ko];
            p0 += DOT4(w0, hv);
            p1 += DOT4(w1, hv);
            p2 += DOT4(w2, hv);
            p3 += DOT4(w3, hv);
        }

        // ---- value-merging butterfly over 32 kc-lanes: 6 shfls ----
        const bool o1 = (kc & 1);
        float sa = o1 ? p0 : p1;
        float ra = __shfl_xor(sa, 1);
        float qa = (o1 ? p1 : p0) + ra;
        float sb = o1 ? p2 : p3;
        float rb = __shfl_xor(sb, 1);
        float qb = (o1 ? p3 : p2) + rb;
        const bool o2 = (kc & 2);
        float sc = o2 ? qa : qb;
        float rc = __shfl_xor(sc, 2);
        float r  = (o2 ? qb : qa) + rc;
        r += __shfl_xor(r, 4);
        r += __shfl_xor(r, 8);
        r += __shfl_xor(r, 16);
        // gather gates 1..3 onto lane kc==0 (3 shfls)
        const float g1 = __shfl_xor(r, 1);
        const float g2 = __shfl_xor(r, 2);
        const float g3 = __shfl_xor(r, 3);

        // ---- cell + publish on lane kc==0 (one per unit) ----
        if (kc == 0) {
            const float gi = r  + xpc0;
            const float gf = g1 + xpc1;
            const float gg = g2 + xpc2;
            const float go = g3 + xpc3;
            const float c  = sigm(gf) * creg + sigm(gi) * tanhf(gg);
            const float h  = sigm(go) * tanhf(c);
            creg = c;
            // publish FIRST (consumers wait on this), hist after
            const unsigned long long pack =
                ((unsigned long long)(unsigned)(t + 1) << 32) |
                (unsigned long long)__float_as_uint(h);
            __hip_atomic_store(&slots[((size_t)((t + 1) & 1) * 2 + dir) * H2DIM + unit],
                               pack, __ATOMIC_RELAXED, __HIP_MEMORY_SCOPE_AGENT);
            const int tg = dir ? (T_LEN - 1 - t) : t;
            hist[(size_t)tg * 2048 + dir * H2DIM + unit] = h;
        }

        // ---- poll peers' h for step t+1; write NEXT-parity hbuf ----
        if (t + 1 < T_LEN) {
            const unsigned want = (unsigned)(t + 1);
            unsigned long long* sb4 = &slots[((size_t)((t + 1) & 1) * 2 + dir) * H2DIM + tid * 4];
            unsigned long long v0 = 0, v1 = 0, v2 = 0, v3 = 0;
            bool d0 = false, d1 = false, d2 = false, d3 = false;
            for (;;) {
                if (!d0) v0 = __hip_atomic_load(&sb4[0], __ATOMIC_RELAXED, __HIP_MEMORY_SCOPE_AGENT);
                if (!d1) v1 = __hip_atomic_load(&sb4[1], __ATOMIC_RELAXED, __HIP_MEMORY_SCOPE_AGENT);
                if (!d2) v2 = __hip_atomic_load(&sb4[2], __ATOMIC_RELAXED, __HIP_MEMORY_SCOPE_AGENT);
                if (!d3) v3 = __hip_atomic_load(&sb4[3], __ATOMIC_RELAXED, __HIP_MEMORY_SCOPE_AGENT);
                d0 = d0 || ((unsigned)(v0 >> 32) == want);
                d1 = d1 || ((unsigned)(v1 >> 32) == want);
                d2 = d2 || ((unsigned)(v2 >> 32) == want);
                d3 = d3 || ((unsigned)(v3 >> 32) == want);
                if (d0 && d1 && d2 && d3) break;
                if (--budget <= 0) break;                // hang-proof bail
                __builtin_amdgcn_s_sleep(1);             // throttle: drain fabric queues
            }
            float4 hv;
            hv.x = __uint_as_float((unsigned)v0);
            hv.y = __uint_as_float((unsigned)v1);
            hv.z = __uint_as_float((unsigned)v2);
            hv.w = __uint_as_float((unsigned)v3);
            *(float4*)&hbuf[(t + 1) & 1][tid * 4] = hv;
        }
        __syncthreads();   // next-parity hbuf complete; safe to proceed
        xpc0 = xpn0; xpc1 = xpn1; xpc2 = xpn2; xpc3 = xpn3;
        xpn0 = xq0;  xpn1 = xq1;  xpn2 = xq2;  xpn3 = xq3;
    }
}

// ============================================================================
// Kernel 3: feats[t][n] = dot(hist[t], w_tag[n]) + b_tag[n]
// ============================================================================
__global__ __launch_bounds__(256)
void feats_kernel(const float* __restrict__ hist,
                  const float* __restrict__ w_tag,
                  const float* __restrict__ b_tag,
                  float* __restrict__ feats)
{
    const int t = blockIdx.x;
    const int tid = threadIdx.x;
    const float* __restrict__ hrow = hist + (size_t)t * 2048 + tid * 8;
    const float4 ha = *(const float4*)&hrow[0];
    const float4 hb = *(const float4*)&hrow[4];
    float p[4];
    #pragma unroll
    for (int n = 0; n < 4; ++n) {
        const float* __restrict__ wr = w_tag + n * 2048 + tid * 8;
        const float4 wa = *(const float4*)&wr[0];
        const float4 wb = *(const float4*)&wr[4];
        p[n] = ha.x*wa.x + ha.y*wa.y + ha.z*wa.z + ha.w*wa.w
             + hb.x*wb.x + hb.y*wb.y + hb.z*wb.z + hb.w*wb.w;
    }
    #pragma unroll
    for (int m = 32; m >= 1; m >>= 1) {
        #pragma unroll
        for (int n = 0; n < 4; ++n) p[n] += __shfl_down(p[n], m);
    }
    __shared__ float red[4][4];
    const int wv = tid >> 6;
    if ((tid & 63) == 0) {
        #pragma unroll
        for (int n = 0; n < 4; ++n) red[n][wv] = p[n];
    }
    __syncthreads();
    if (tid < 4)
        feats[(size_t)t * 4 + tid] = red[tid][0] + red[tid][1] + red[tid][2] + red[tid][3] + b_tag[tid];
}

// ============================================================================
// Kernel 4: Viterbi (4 tags): forward DP + backtrace, op-order matches ref.
// ============================================================================
__global__ __launch_bounds__(256)
void viterbi_kernel(const float* __restrict__ feats,
                    const float* __restrict__ trans,
                    float* __restrict__ out)
{
    __shared__ float fsh[T_LEN * 4];   // 64 KB
    __shared__ unsigned bp[T_LEN];     // 16 KB
    const int tid = threadIdx.x;
    for (int i = tid; i < T_LEN; i += 256)
        *(float4*)&fsh[i * 4] = *(const float4*)&feats[(size_t)i * 4];
    __syncthreads();
    if (tid == 0) {
        float tr[16];
        #pragma unroll
        for (int i = 0; i < 16; ++i) tr[i] = trans[i];
        float fv[4] = {NEGV, NEGV, NEGV, NEGV};
        fv[START_TAG] = 0.0f;
        for (int t = 0; t < T_LEN; ++t) {
            float nf[4]; unsigned pb = 0;
            #pragma unroll
            for (int n = 0; n < 4; ++n) {
                float m = fv[0] + tr[n * 4 + 0]; int bsel = 0;
                #pragma unroll
                for (int p = 1; p < 4; ++p) {
                    const float s = fv[p] + tr[n * 4 + p];
                    if (s > m) { m = s; bsel = p; }
                }
                nf[n] = m + fsh[t * 4 + n];
                pb |= (unsigned)bsel << (8 * n);
            }
            bp[t] = pb;
            fv[0] = nf[0]; fv[1] = nf[1]; fv[2] = nf[2]; fv[3] = nf[3];
        }
        float bm = fv[0] + tr[STOP_TAG * 4 + 0]; int best = 0;
        #pragma unroll
        for (int p = 1; p < 4; ++p) {
            const float s = fv[p] + tr[STOP_TAG * 4 + p];
            if (s > bm) { bm = s; best = p; }
        }
        out[0] = bm;
        int cur = best;
        for (int t = T_LEN - 1; t >= 0; --t) {
            out[1 + t] = (float)cur;
            cur = (int)((bp[t] >> (8 * cur)) & 0xffu);
        }
    }
}

// ============================================================================
extern "C" void kernel_launch(void* const* d_in, const int* in_sizes, int n_in,
                              void* d_out, int out_size, void* d_ws, size_t ws_size,
                              hipStream_t stream) {
    const float* x      = (const float*)d_in[0];
    const float* h0     = (const float*)d_in[1];
    const float* c0     = (const float*)d_in[2];
    const float* w_ih_f = (const float*)d_in[3];
    const float* w_hh_f = (const float*)d_in[4];
    const float* b_ih_f = (const float*)d_in[5];
    const float* b_hh_f = (const float*)d_in[6];
    const float* w_ih_b = (const float*)d_in[7];
    const float* w_hh_b = (const float*)d_in[8];
    const float* b_ih_b = (const float*)d_in[9];
    const float* b_hh_b = (const float*)d_in[10];
    const float* w_tag  = (const float*)d_in[11];
    const float* b_tag  = (const float*)d_in[12];
    const float* trans  = (const float*)d_in[13];
    float* out = (float*)d_out;

    if (ws_size < WS_NEED) return;   // signature: output stays poisoned

    char* ws = (char*)d_ws;
    float* xp    = (float*)(ws + XP_OFF);
    float* hist  = (float*)(ws + HIST_OFF);
    float* feats = (float*)(ws + FEATS_OFF);
    unsigned long long* slots = (unsigned long long*)(ws + SLOTS_OFF);

    hipMemsetAsync(slots, 0, SLOTS_BYTES, stream);

    dim3 ggrid(32, 32, 2);
    xp_gemm<<<ggrid, 256, 0, stream>>>(x, w_ih_f, w_ih_b, b_ih_f, b_hh_f, b_ih_b, b_hh_b, xp);

    void* ka[] = { (void*)&xp, (void*)&h0, (void*)&c0, (void*)&w_hh_f, (void*)&w_hh_b,
                   (void*)&hist, (void*)&slots };
    hipLaunchCooperativeKernel((void*)lstm_scan, dim3(256), dim3(256), ka, 0, stream);

    feats_kernel<<<T_LEN, 256, 0, stream>>>(hist, w_tag, b_tag, feats);
    viterbi_kernel<<<1, 256, 0, stream>>>(feats, trans, out);
}

// Round 9
// 14325.418 us; speedup vs baseline: 1.3151x; 1.3151x over previous
//
#include <hip/hip_runtime.h>
#include <cstddef>
#include <cstdint>

#define T_LEN 4096
#define FDIM  1024
#define H2DIM 1024
#define GDIM  4096   // 4*H2

#define NEGV (-10000.0f)
#define START_TAG 2
#define STOP_TAG 3

// ---- workspace layout (bytes) ----
#define XP_OFF      ((size_t)0)
#define XP_BYTES    ((size_t)2 * T_LEN * GDIM * 4)          // 134,217,728
#define HIST_OFF    (XP_OFF + XP_BYTES)
#define HIST_BYTES  ((size_t)T_LEN * 2048 * 4)              // 33,554,432
#define FEATS_OFF   (HIST_OFF + HIST_BYTES)
#define FEATS_BYTES ((size_t)T_LEN * 4 * 4)
#define SLOTS_OFF   (FEATS_OFF + FEATS_BYTES)
#define SLOTS_BYTES ((size_t)2 * 2 * 1024 * 8)              // parity x dir x unit, u64
#define WS_NEED     (SLOTS_OFF + SLOTS_BYTES)

// bf16 staging buffers live INSIDE the hist region (dead until the scan runs;
// the gemm finishes reading them before lstm_scan overwrites hist).
#define XB_OFF      (HIST_OFF)                               // 8 MB
#define WBF_OFF     (HIST_OFF + (size_t)8  * 1024 * 1024)    // 8 MB
#define WBB_OFF     (HIST_OFF + (size_t)16 * 1024 * 1024)    // 8 MB

__device__ __forceinline__ float sigm(float x) { return 1.0f / (1.0f + expf(-x)); }

__device__ __forceinline__ unsigned short f2bf(float f) {
    unsigned u = __float_as_uint(f);
    return (unsigned short)((u + 0x7FFFu + ((u >> 16) & 1u)) >> 16);   // RNE
}

typedef short  bf16x8 __attribute__((ext_vector_type(8)));
typedef float  f32x4  __attribute__((ext_vector_type(4)));

// ============================================================================
// Kernel 0: fp32 -> bf16 (RNE), vectorized grid-stride
// ============================================================================
__global__ __launch_bounds__(256)
void conv_bf16(const float* __restrict__ src, unsigned short* __restrict__ dst, int n4)
{
    int i = blockIdx.x * 256 + threadIdx.x;
    const int stride = gridDim.x * 256;
    for (; i < n4; i += stride) {
        const float4 v = ((const float4*)src)[i];
        ushort4 o;
        o.x = f2bf(v.x); o.y = f2bf(v.y); o.z = f2bf(v.z); o.w = f2bf(v.w);
        ((ushort4*)dst)[i] = o;
    }
}

// ============================================================================
// Kernel 1: bf16 MFMA input GEMM.
// xp[dir][s][j] = dot(x[row(s)], w_ih_dir[j]) + b_ih[j] + b_hh[j], fp32 out.
// One wave per block, 64x64 output tile = 4x4 frags of mfma_f32_16x16x32_bf16.
// No LDS: fragments loaded directly from global (lane quads {l,l+16,l+32,l+48}
// read 64B contiguous per row -> fully-used lines; L2/LLC serves reuse).
// Layouts (m89-verified family): A: lane l -> row l&15, k=(l>>4)*8+i.
// B: lane l -> col l&15, k=(l>>4)*8+i.  D: col l&15, row (l>>4)*4+j.
// ============================================================================
__global__ __launch_bounds__(64)
void xp_gemm_mfma(const unsigned short* __restrict__ xb,
                  const unsigned short* __restrict__ wb_f,
                  const unsigned short* __restrict__ wb_b,
                  const float* __restrict__ bi_f, const float* __restrict__ bh_f,
                  const float* __restrict__ bi_b, const float* __restrict__ bh_b,
                  float* __restrict__ xp)
{
    const int lane = threadIdx.x;
    const int j0   = blockIdx.x * 64;
    const int t0   = blockIdx.y * 64;
    const int dir  = blockIdx.z;
    const unsigned short* __restrict__ wb = dir ? wb_b : wb_f;
    const float* __restrict__ bi = dir ? bi_b : bi_f;
    const float* __restrict__ bh = dir ? bh_b : bh_f;

    const int r  = lane & 15;
    const int kg = lane >> 4;          // k-group 0..3 -> k offset kg*8

    const unsigned short* arow[4];
    const unsigned short* brow[4];
    #pragma unroll
    for (int s = 0; s < 4; ++s) {
        const int tg = t0 + s * 16 + r;
        const int sr = dir ? (T_LEN - 1 - tg) : tg;       // scan-order row
        arow[s] = xb + (size_t)sr * FDIM + kg * 8;
        brow[s] = wb + (size_t)(j0 + s * 16 + r) * FDIM + kg * 8;
    }

    f32x4 acc[4][4];
    #pragma unroll
    for (int sm = 0; sm < 4; ++sm)
        #pragma unroll
        for (int sn = 0; sn < 4; ++sn)
            acc[sm][sn] = (f32x4){0.f, 0.f, 0.f, 0.f};

    for (int k0 = 0; k0 < FDIM; k0 += 32) {
        bf16x8 a[4], b[4];
        #pragma unroll
        for (int s = 0; s < 4; ++s) {
            a[s] = *(const bf16x8*)(arow[s] + k0);
            b[s] = *(const bf16x8*)(brow[s] + k0);
        }
        #pragma unroll
        for (int sm = 0; sm < 4; ++sm)
            #pragma unroll
            for (int sn = 0; sn < 4; ++sn)
                acc[sm][sn] = __builtin_amdgcn_mfma_f32_16x16x32_bf16(
                                  a[sm], b[sn], acc[sm][sn], 0, 0, 0);
    }

    float* __restrict__ xpd = xp + (size_t)dir * T_LEN * GDIM;
    #pragma unroll
    for (int sn = 0; sn < 4; ++sn) {
        const int col  = j0 + sn * 16 + r;
        const float bv = bi[col] + bh[col];
        #pragma unroll
        for (int sm = 0; sm < 4; ++sm) {
            #pragma unroll
            for (int j = 0; j < 4; ++j) {
                const int row = t0 + sm * 16 + kg * 4 + j;
                xpd[(size_t)row * GDIM + col] = acc[sm][sn][j] + bv;
            }
        }
    }
}

// ============================================================================
// Kernel 2: cooperative persistent bidirectional LSTM scan.
// BIT-EXACT copy of the R2 kernel (measured 13.28 ms): 256x256, w_hh in LDS
// (gate-major), gsh roundtrip + 2 barriers, WAVE-COALESCED publish from tid<8
// (single 64B atomic store per block-step -> one full-line fabric transaction;
// the R3+ per-wave split publish cost +67MB writebacks and +0.8us/step).
// Poll: 4 agent atomic loads + s_sleep(1), budget 4M.
// ============================================================================
__global__ __launch_bounds__(256, 1)
void lstm_scan(const float* __restrict__ xp,
               const float* __restrict__ h0,
               const float* __restrict__ c0,
               const float* __restrict__ whh_f,
               const float* __restrict__ whh_b,
               float* __restrict__ hist,
               unsigned long long* __restrict__ slots)
{
    __shared__ float wsl[32][1024];   // 131072 B
    __shared__ float hbuf[1024];      //   4096 B
    __shared__ float gsh[32];

    const int tid = threadIdx.x;
    const int b   = blockIdx.x;
    const int dir = b >> 7;
    const int bi  = b & 127;
    const int u0  = bi * 8;
    const int rg  = tid >> 5;   // 0..7  (row group: 4 rows)
    const int kc  = tid & 31;   // 0..31 (k chunk)
    const int lrb = rg * 4;

    const float* __restrict__ whh = dir ? whh_b : whh_f;
    const size_t xpbase = (size_t)dir * T_LEN * GDIM;

    // stage w_hh slice: local row lr = gate*8 + u  ->  global row gate*1024 + u0 + u
    for (int lr = 0; lr < 32; ++lr) {
        const int grow = ((lr >> 3) << 10) + u0 + (lr & 7);
        *(float4*)&wsl[lr][tid * 4] = *(const float4*)&whh[(size_t)grow * H2DIM + tid * 4];
    }
    *(float4*)&hbuf[tid * 4] = *(const float4*)&h0[dir * H2DIM + tid * 4];
    float creg = 0.f;
    if (tid < 8) creg = c0[dir * H2DIM + u0 + tid];

    int grows[4];
    #pragma unroll
    for (int j = 0; j < 4; ++j) {
        const int lr = lrb + j;
        grows[j] = ((lr >> 3) << 10) + u0 + (lr & 7);
    }
    float xpc[4] = {0.f, 0.f, 0.f, 0.f};
    if (kc == 0) {
        #pragma unroll
        for (int j = 0; j < 4; ++j) xpc[j] = xp[xpbase + grows[j]];
    }
    __syncthreads();

    int budget = 4000000;   // total poll iterations per thread across all steps

    for (int t = 0; t < T_LEN; ++t) {
        // prefetch next step's xp (hides HBM latency under this step's compute)
        float xpn[4] = {0.f, 0.f, 0.f, 0.f};
        const int tnx = (t + 1 < T_LEN) ? (t + 1) : t;
        if (kc == 0) {
            #pragma unroll
            for (int j = 0; j < 4; ++j) xpn[j] = xp[xpbase + (size_t)tnx * GDIM + grows[j]];
        }

        // partial dots: 4 rows x 32 k-elems (contiguous b128 reads, conflict-free)
        float p0 = 0.f, p1 = 0.f, p2 = 0.f, p3 = 0.f;
        #pragma unroll
        for (int s = 0; s < 8; ++s) {
            const int ko = s * 128 + kc * 4;
            const float4 hv = *(const float4*)&hbuf[ko];
            const float4 w0 = *(const float4*)&wsl[lrb + 0][ko];
            const float4 w1 = *(const float4*)&wsl[lrb + 1][ko];
            const float4 w2 = *(const float4*)&wsl[lrb + 2][ko];
            const float4 w3 = *(const float4*)&wsl[lrb + 3][ko];
            p0 += w0.x*hv.x + w0.y*hv.y + w0.z*hv.z + w0.w*hv.w;
            p1 += w1.x*hv.x + w1.y*hv.y + w1.z*hv.z + w1.w*hv.w;
            p2 += w2.x*hv.x + w2.y*hv.y + w2.z*hv.z + w2.w*hv.w;
            p3 += w3.x*hv.x + w3.y*hv.y + w3.z*hv.z + w3.w*hv.w;
        }
        // reduce over the 32 kc lanes (butterfly stays within each 32-lane half)
        #pragma unroll
        for (int m = 16; m >= 1; m >>= 1) {
            p0 += __shfl_xor(p0, m);
            p1 += __shfl_xor(p1, m);
            p2 += __shfl_xor(p2, m);
            p3 += __shfl_xor(p3, m);
        }
        if (kc == 0) {
            gsh[lrb + 0] = p0 + xpc[0];
            gsh[lrb + 1] = p1 + xpc[1];
            gsh[lrb + 2] = p2 + xpc[2];
            gsh[lrb + 3] = p3 + xpc[3];
        }
        __syncthreads();

        // LSTM cell on 8 threads (one per hidden unit) -- wave-coalesced publish
        if (tid < 8) {
            const float gi = gsh[tid];
            const float gf = gsh[8 + tid];
            const float gg = gsh[16 + tid];
            const float go = gsh[24 + tid];
            const float c  = sigm(gf) * creg + sigm(gi) * tanhf(gg);
            const float h  = sigm(go) * tanhf(c);
            creg = c;
            const int tg = dir ? (T_LEN - 1 - t) : t;
            hist[(size_t)tg * 2048 + dir * H2DIM + u0 + tid] = h;
            const unsigned long long pack =
                ((unsigned long long)(unsigned)(t + 1) << 32) |
                (unsigned long long)__float_as_uint(h);
            __hip_atomic_store(&slots[((size_t)((t + 1) & 1) * 2 + dir) * H2DIM + u0 + tid],
                               pack, __ATOMIC_RELAXED, __HIP_MEMORY_SCOPE_AGENT);
        }

        // poll peers' h slots for tag t+1 (4 independent loads per sweep -> ILP)
        if (t + 1 < T_LEN) {
            const unsigned want = (unsigned)(t + 1);
            unsigned long long* sb = &slots[((size_t)((t + 1) & 1) * 2 + dir) * H2DIM + tid * 4];
            unsigned long long v0 = 0, v1 = 0, v2 = 0, v3 = 0;
            bool g0 = false, g1 = false, g2 = false, g3 = false;
            for (;;) {
                if (!g0) v0 = __hip_atomic_load(&sb[0], __ATOMIC_RELAXED, __HIP_MEMORY_SCOPE_AGENT);
                if (!g1) v1 = __hip_atomic_load(&sb[1], __ATOMIC_RELAXED, __HIP_MEMORY_SCOPE_AGENT);
                if (!g2) v2 = __hip_atomic_load(&sb[2], __ATOMIC_RELAXED, __HIP_MEMORY_SCOPE_AGENT);
                if (!g3) v3 = __hip_atomic_load(&sb[3], __ATOMIC_RELAXED, __HIP_MEMORY_SCOPE_AGENT);
                g0 = g0 || ((unsigned)(v0 >> 32) == want);
                g1 = g1 || ((unsigned)(v1 >> 32) == want);
                g2 = g2 || ((unsigned)(v2 >> 32) == want);
                g3 = g3 || ((unsigned)(v3 >> 32) == want);
                if (g0 && g1 && g2 && g3) break;
                if (--budget <= 0) break;                // hang-proof: bail, wrong-but-finite
                __builtin_amdgcn_s_sleep(1);             // backoff: reduce LLC atomic pressure
            }
            float4 hv;
            hv.x = __uint_as_float((unsigned)v0);
            hv.y = __uint_as_float((unsigned)v1);
            hv.z = __uint_as_float((unsigned)v2);
            hv.w = __uint_as_float((unsigned)v3);
            *(float4*)&hbuf[tid * 4] = hv;
        }
        __syncthreads();
        if (kc == 0) { xpc[0] = xpn[0]; xpc[1] = xpn[1]; xpc[2] = xpn[2]; xpc[3] = xpn[3]; }
    }
}

// ============================================================================
// Kernel 3: feats[t][n] = dot(hist[t], w_tag[n]) + b_tag[n]
// ============================================================================
__global__ __launch_bounds__(256)
void feats_kernel(const float* __restrict__ hist,
                  const float* __restrict__ w_tag,
                  const float* __restrict__ b_tag,
                  float* __restrict__ feats)
{
    const int t = blockIdx.x;
    const int tid = threadIdx.x;
    const float* __restrict__ hrow = hist + (size_t)t * 2048 + tid * 8;
    const float4 ha = *(const float4*)&hrow[0];
    const float4 hb = *(const float4*)&hrow[4];
    float p[4];
    #pragma unroll
    for (int n = 0; n < 4; ++n) {
        const float* __restrict__ wr = w_tag + n * 2048 + tid * 8;
        const float4 wa = *(const float4*)&wr[0];
        const float4 wb = *(const float4*)&wr[4];
        p[n] = ha.x*wa.x + ha.y*wa.y + ha.z*wa.z + ha.w*wa.w
             + hb.x*wb.x + hb.y*wb.y + hb.z*wb.z + hb.w*wb.w;
    }
    #pragma unroll
    for (int m = 32; m >= 1; m >>= 1) {
        #pragma unroll
        for (int n = 0; n < 4; ++n) p[n] += __shfl_down(p[n], m);
    }
    __shared__ float red[4][4];
    const int wv = tid >> 6;
    if ((tid & 63) == 0) {
        #pragma unroll
        for (int n = 0; n < 4; ++n) red[n][wv] = p[n];
    }
    __syncthreads();
    if (tid < 4)
        feats[(size_t)t * 4 + tid] = red[tid][0] + red[tid][1] + red[tid][2] + red[tid][3] + b_tag[tid];
}

// ============================================================================
// Kernel 4: Viterbi (4 tags): forward DP + backtrace, op-order matches ref.
// ============================================================================
__global__ __launch_bounds__(256)
void viterbi_kernel(const float* __restrict__ feats,
                    const float* __restrict__ trans,
                    float* __restrict__ out)
{
    __shared__ float fsh[T_LEN * 4];   // 64 KB
    __shared__ unsigned bp[T_LEN];     // 16 KB
    const int tid = threadIdx.x;
    for (int i = tid; i < T_LEN; i += 256)
        *(float4*)&fsh[i * 4] = *(const float4*)&feats[(size_t)i * 4];
    __syncthreads();
    if (tid == 0) {
        float tr[16];
        #pragma unroll
        for (int i = 0; i < 16; ++i) tr[i] = trans[i];
        float fv[4] = {NEGV, NEGV, NEGV, NEGV};
        fv[START_TAG] = 0.0f;
        for (int t = 0; t < T_LEN; ++t) {
            float nf[4]; unsigned pb = 0;
            #pragma unroll
            for (int n = 0; n < 4; ++n) {
                float m = fv[0] + tr[n * 4 + 0]; int bsel = 0;
                #pragma unroll
                for (int p = 1; p < 4; ++p) {
                    const float s = fv[p] + tr[n * 4 + p];
                    if (s > m) { m = s; bsel = p; }
                }
                nf[n] = m + fsh[t * 4 + n];
                pb |= (unsigned)bsel << (8 * n);
            }
            bp[t] = pb;
            fv[0] = nf[0]; fv[1] = nf[1]; fv[2] = nf[2]; fv[3] = nf[3];
        }
        float bm = fv[0] + tr[STOP_TAG * 4 + 0]; int best = 0;
        #pragma unroll
        for (int p = 1; p < 4; ++p) {
            const float s = fv[p] + tr[STOP_TAG * 4 + p];
            if (s > bm) { bm = s; best = p; }
        }
        out[0] = bm;
        int cur = best;
        for (int t = T_LEN - 1; t >= 0; --t) {
            out[1 + t] = (float)cur;
            cur = (int)((bp[t] >> (8 * cur)) & 0xffu);
        }
    }
}

// ============================================================================
extern "C" void kernel_launch(void* const* d_in, const int* in_sizes, int n_in,
                              void* d_out, int out_size, void* d_ws, size_t ws_size,
                              hipStream_t stream) {
    const float* x      = (const float*)d_in[0];
    const float* h0     = (const float*)d_in[1];
    const float* c0     = (const float*)d_in[2];
    const float* w_ih_f = (const float*)d_in[3];
    const float* w_hh_f = (const float*)d_in[4];
    const float* b_ih_f = (const float*)d_in[5];
    const float* b_hh_f = (const float*)d_in[6];
    const float* w_ih_b = (const float*)d_in[7];
    const float* w_hh_b = (const float*)d_in[8];
    const float* b_ih_b = (const float*)d_in[9];
    const float* b_hh_b = (const float*)d_in[10];
    const float* w_tag  = (const float*)d_in[11];
    const float* b_tag  = (const float*)d_in[12];
    const float* trans  = (const float*)d_in[13];
    float* out = (float*)d_out;

    if (ws_size < WS_NEED) return;   // signature: output stays poisoned

    char* ws = (char*)d_ws;
    float* xp    = (float*)(ws + XP_OFF);
    float* hist  = (float*)(ws + HIST_OFF);
    float* feats = (float*)(ws + FEATS_OFF);
    unsigned long long* slots = (unsigned long long*)(ws + SLOTS_OFF);
    unsigned short* xb  = (unsigned short*)(ws + XB_OFF);
    unsigned short* wbf = (unsigned short*)(ws + WBF_OFF);
    unsigned short* wbb = (unsigned short*)(ws + WBB_OFF);

    hipMemsetAsync(slots, 0, SLOTS_BYTES, stream);

    // fp32 -> bf16 staging (x, w_ih_f, w_ih_b); each 4096x1024 elems -> n4 = 1M
    const int n4 = (T_LEN * FDIM) / 4;
    conv_bf16<<<1024, 256, 0, stream>>>(x,      xb,  n4);
    conv_bf16<<<1024, 256, 0, stream>>>(w_ih_f, wbf, n4);
    conv_bf16<<<1024, 256, 0, stream>>>(w_ih_b, wbb, n4);

    // bf16 MFMA input GEMM (reads xb/wbf/wbb from the hist region, writes xp)
    xp_gemm_mfma<<<dim3(64, 64, 2), 64, 0, stream>>>(
        xb, wbf, wbb, b_ih_f, b_hh_f, b_ih_b, b_hh_b, xp);

    // scan overwrites the hist region only after the gemm has consumed xb/wb*
    void* ka[] = { (void*)&xp, (void*)&h0, (void*)&c0, (void*)&w_hh_f, (void*)&w_hh_b,
                   (void*)&hist, (void*)&slots };
    hipLaunchCooperativeKernel((void*)lstm_scan, dim3(256), dim3(256), ka, 0, stream);

    feats_kernel<<<T_LEN, 256, 0, stream>>>(hist, w_tag, b_tag, feats);
    viterbi_kernel<<<1, 256, 0, stream>>>(feats, trans, out);
}

// Round 10
// 14008.157 us; speedup vs baseline: 1.3449x; 1.0226x over previous
//
#include <hip/hip_runtime.h>
#include <cstddef>
#include <cstdint>

#define T_LEN 4096
#define FDIM  1024
#define H2DIM 1024
#define GDIM  4096   // 4*H2

#define NEGV (-10000.0f)
#define START_TAG 2
#define STOP_TAG 3

// ---- workspace layout (bytes) ----
#define XP_OFF      ((size_t)0)
#define XP_BYTES    ((size_t)2 * T_LEN * GDIM * 4)          // 134,217,728
#define HIST_OFF    (XP_OFF + XP_BYTES)
#define HIST_BYTES  ((size_t)T_LEN * 2048 * 4)              // 33,554,432
#define FEATS_OFF   (HIST_OFF + HIST_BYTES)
#define FEATS_BYTES ((size_t)T_LEN * 4 * 4)
#define SLOTS_OFF   (FEATS_OFF + FEATS_BYTES)
#define SLOTS_BYTES ((size_t)2 * 2 * 1024 * 8)              // parity x dir x unit, u64
#define WS_NEED     (SLOTS_OFF + SLOTS_BYTES)

// bf16 staging buffers live INSIDE the hist region (dead until the scan runs;
// the gemm finishes reading them before lstm_scan overwrites hist).
#define XB_OFF      (HIST_OFF)                               // 8 MB
#define WBF_OFF     (HIST_OFF + (size_t)8  * 1024 * 1024)    // 8 MB
#define WBB_OFF     (HIST_OFF + (size_t)16 * 1024 * 1024)    // 8 MB

__device__ __forceinline__ float sigm(float x) { return 1.0f / (1.0f + expf(-x)); }

__device__ __forceinline__ unsigned short f2bf(float f) {
    unsigned u = __float_as_uint(f);
    return (unsigned short)((u + 0x7FFFu + ((u >> 16) & 1u)) >> 16);   // RNE
}

// compose two 4-element tag maps packed as u32 (byte c = map(c), values 0..3):
// (A o B)(c) = A(B(c)).  Exact integer op -> path bit-identical to serial.
__device__ __forceinline__ unsigned compose4(unsigned A, unsigned B) {
    unsigned r = 0;
    #pragma unroll
    for (int c = 0; c < 4; ++c) {
        const unsigned b = (B >> (8 * c)) & 3u;
        const unsigned a = (A >> (8 * b)) & 3u;
        r |= a << (8 * c);
    }
    return r;
}

typedef short  bf16x8 __attribute__((ext_vector_type(8)));
typedef float  f32x4  __attribute__((ext_vector_type(4)));

// ============================================================================
// Kernel 0: fp32 -> bf16 (RNE), vectorized grid-stride
// ============================================================================
__global__ __launch_bounds__(256)
void conv_bf16(const float* __restrict__ src, unsigned short* __restrict__ dst, int n4)
{
    int i = blockIdx.x * 256 + threadIdx.x;
    const int stride = gridDim.x * 256;
    for (; i < n4; i += stride) {
        const float4 v = ((const float4*)src)[i];
        ushort4 o;
        o.x = f2bf(v.x); o.y = f2bf(v.y); o.z = f2bf(v.z); o.w = f2bf(v.w);
        ((ushort4*)dst)[i] = o;
    }
}

// ============================================================================
// Kernel 1: bf16 MFMA input GEMM (unchanged from R9; absmax=0 verified).
// xp[dir][s][j] = dot(x[row(s)], w_ih_dir[j]) + b_ih[j] + b_hh[j], fp32 out.
// ============================================================================
__global__ __launch_bounds__(64)
void xp_gemm_mfma(const unsigned short* __restrict__ xb,
                  const unsigned short* __restrict__ wb_f,
                  const unsigned short* __restrict__ wb_b,
                  const float* __restrict__ bi_f, const float* __restrict__ bh_f,
                  const float* __restrict__ bi_b, const float* __restrict__ bh_b,
                  float* __restrict__ xp)
{
    const int lane = threadIdx.x;
    const int j0   = blockIdx.x * 64;
    const int t0   = blockIdx.y * 64;
    const int dir  = blockIdx.z;
    const unsigned short* __restrict__ wb = dir ? wb_b : wb_f;
    const float* __restrict__ bi = dir ? bi_b : bi_f;
    const float* __restrict__ bh = dir ? bh_b : bh_f;

    const int r  = lane & 15;
    const int kg = lane >> 4;          // k-group 0..3 -> k offset kg*8

    const unsigned short* arow[4];
    const unsigned short* brow[4];
    #pragma unroll
    for (int s = 0; s < 4; ++s) {
        const int tg = t0 + s * 16 + r;
        const int sr = dir ? (T_LEN - 1 - tg) : tg;       // scan-order row
        arow[s] = xb + (size_t)sr * FDIM + kg * 8;
        brow[s] = wb + (size_t)(j0 + s * 16 + r) * FDIM + kg * 8;
    }

    f32x4 acc[4][4];
    #pragma unroll
    for (int sm = 0; sm < 4; ++sm)
        #pragma unroll
        for (int sn = 0; sn < 4; ++sn)
            acc[sm][sn] = (f32x4){0.f, 0.f, 0.f, 0.f};

    for (int k0 = 0; k0 < FDIM; k0 += 32) {
        bf16x8 a[4], b[4];
        #pragma unroll
        for (int s = 0; s < 4; ++s) {
            a[s] = *(const bf16x8*)(arow[s] + k0);
            b[s] = *(const bf16x8*)(brow[s] + k0);
        }
        #pragma unroll
        for (int sm = 0; sm < 4; ++sm)
            #pragma unroll
            for (int sn = 0; sn < 4; ++sn)
                acc[sm][sn] = __builtin_amdgcn_mfma_f32_16x16x32_bf16(
                                  a[sm], b[sn], acc[sm][sn], 0, 0, 0);
    }

    float* __restrict__ xpd = xp + (size_t)dir * T_LEN * GDIM;
    #pragma unroll
    for (int sn = 0; sn < 4; ++sn) {
        const int col  = j0 + sn * 16 + r;
        const float bv = bi[col] + bh[col];
        #pragma unroll
        for (int sm = 0; sm < 4; ++sm) {
            #pragma unroll
            for (int j = 0; j < 4; ++j) {
                const int row = t0 + sm * 16 + kg * 4 + j;
                xpd[(size_t)row * GDIM + col] = acc[sm][sn][j] + bv;
            }
        }
    }
}

// ============================================================================
// Kernel 2: cooperative persistent bidirectional LSTM scan.
// R2-proven structure, ONE change: dir = b&1 (was b>>7). With round-robin
// block->XCD mapping, each direction's 128 communicating blocks now occupy
// 4 XCDs instead of 8 -> shorter publish/poll fabric paths. Perf-only.
// ============================================================================
__global__ __launch_bounds__(256, 1)
void lstm_scan(const float* __restrict__ xp,
               const float* __restrict__ h0,
               const float* __restrict__ c0,
               const float* __restrict__ whh_f,
               const float* __restrict__ whh_b,
               float* __restrict__ hist,
               unsigned long long* __restrict__ slots)
{
    __shared__ float wsl[32][1024];   // 131072 B
    __shared__ float hbuf[1024];      //   4096 B
    __shared__ float gsh[32];

    const int tid = threadIdx.x;
    const int b   = blockIdx.x;
    const int dir = b & 1;            // XCD swizzle: fwd on even XCDs, bwd odd
    const int bi  = b >> 1;
    const int u0  = bi * 8;
    const int rg  = tid >> 5;   // 0..7  (row group: 4 rows)
    const int kc  = tid & 31;   // 0..31 (k chunk)
    const int lrb = rg * 4;

    const float* __restrict__ whh = dir ? whh_b : whh_f;
    const size_t xpbase = (size_t)dir * T_LEN * GDIM;

    // stage w_hh slice: local row lr = gate*8 + u  ->  global row gate*1024 + u0 + u
    for (int lr = 0; lr < 32; ++lr) {
        const int grow = ((lr >> 3) << 10) + u0 + (lr & 7);
        *(float4*)&wsl[lr][tid * 4] = *(const float4*)&whh[(size_t)grow * H2DIM + tid * 4];
    }
    *(float4*)&hbuf[tid * 4] = *(const float4*)&h0[dir * H2DIM + tid * 4];
    float creg = 0.f;
    if (tid < 8) creg = c0[dir * H2DIM + u0 + tid];

    int grows[4];
    #pragma unroll
    for (int j = 0; j < 4; ++j) {
        const int lr = lrb + j;
        grows[j] = ((lr >> 3) << 10) + u0 + (lr & 7);
    }
    float xpc[4] = {0.f, 0.f, 0.f, 0.f};
    if (kc == 0) {
        #pragma unroll
        for (int j = 0; j < 4; ++j) xpc[j] = xp[xpbase + grows[j]];
    }
    __syncthreads();

    int budget = 4000000;   // total poll iterations per thread across all steps

    for (int t = 0; t < T_LEN; ++t) {
        // prefetch next step's xp (hides HBM latency under this step's compute)
        float xpn[4] = {0.f, 0.f, 0.f, 0.f};
        const int tnx = (t + 1 < T_LEN) ? (t + 1) : t;
        if (kc == 0) {
            #pragma unroll
            for (int j = 0; j < 4; ++j) xpn[j] = xp[xpbase + (size_t)tnx * GDIM + grows[j]];
        }

        // partial dots: 4 rows x 32 k-elems (contiguous b128 reads, conflict-free)
        float p0 = 0.f, p1 = 0.f, p2 = 0.f, p3 = 0.f;
        #pragma unroll
        for (int s = 0; s < 8; ++s) {
            const int ko = s * 128 + kc * 4;
            const float4 hv = *(const float4*)&hbuf[ko];
            const float4 w0 = *(const float4*)&wsl[lrb + 0][ko];
            const float4 w1 = *(const float4*)&wsl[lrb + 1][ko];
            const float4 w2 = *(const float4*)&wsl[lrb + 2][ko];
            const float4 w3 = *(const float4*)&wsl[lrb + 3][ko];
            p0 += w0.x*hv.x + w0.y*hv.y + w0.z*hv.z + w0.w*hv.w;
            p1 += w1.x*hv.x + w1.y*hv.y + w1.z*hv.z + w1.w*hv.w;
            p2 += w2.x*hv.x + w2.y*hv.y + w2.z*hv.z + w2.w*hv.w;
            p3 += w3.x*hv.x + w3.y*hv.y + w3.z*hv.z + w3.w*hv.w;
        }
        // reduce over the 32 kc lanes (butterfly stays within each 32-lane half)
        #pragma unroll
        for (int m = 16; m >= 1; m >>= 1) {
            p0 += __shfl_xor(p0, m);
            p1 += __shfl_xor(p1, m);
            p2 += __shfl_xor(p2, m);
            p3 += __shfl_xor(p3, m);
        }
        if (kc == 0) {
            gsh[lrb + 0] = p0 + xpc[0];
            gsh[lrb + 1] = p1 + xpc[1];
            gsh[lrb + 2] = p2 + xpc[2];
            gsh[lrb + 3] = p3 + xpc[3];
        }
        __syncthreads();

        // LSTM cell on 8 threads (one per hidden unit) -- wave-coalesced publish
        if (tid < 8) {
            const float gi = gsh[tid];
            const float gf = gsh[8 + tid];
            const float gg = gsh[16 + tid];
            const float go = gsh[24 + tid];
            const float c  = sigm(gf) * creg + sigm(gi) * tanhf(gg);
            const float h  = sigm(go) * tanhf(c);
            creg = c;
            const int tg = dir ? (T_LEN - 1 - t) : t;
            hist[(size_t)tg * 2048 + dir * H2DIM + u0 + tid] = h;
            const unsigned long long pack =
                ((unsigned long long)(unsigned)(t + 1) << 32) |
                (unsigned long long)__float_as_uint(h);
            __hip_atomic_store(&slots[((size_t)((t + 1) & 1) * 2 + dir) * H2DIM + u0 + tid],
                               pack, __ATOMIC_RELAXED, __HIP_MEMORY_SCOPE_AGENT);
        }

        // poll peers' h slots for tag t+1 (4 independent loads per sweep -> ILP)
        if (t + 1 < T_LEN) {
            const unsigned want = (unsigned)(t + 1);
            unsigned long long* sb = &slots[((size_t)((t + 1) & 1) * 2 + dir) * H2DIM + tid * 4];
            unsigned long long v0 = 0, v1 = 0, v2 = 0, v3 = 0;
            bool g0 = false, g1 = false, g2 = false, g3 = false;
            for (;;) {
                if (!g0) v0 = __hip_atomic_load(&sb[0], __ATOMIC_RELAXED, __HIP_MEMORY_SCOPE_AGENT);
                if (!g1) v1 = __hip_atomic_load(&sb[1], __ATOMIC_RELAXED, __HIP_MEMORY_SCOPE_AGENT);
                if (!g2) v2 = __hip_atomic_load(&sb[2], __ATOMIC_RELAXED, __HIP_MEMORY_SCOPE_AGENT);
                if (!g3) v3 = __hip_atomic_load(&sb[3], __ATOMIC_RELAXED, __HIP_MEMORY_SCOPE_AGENT);
                g0 = g0 || ((unsigned)(v0 >> 32) == want);
                g1 = g1 || ((unsigned)(v1 >> 32) == want);
                g2 = g2 || ((unsigned)(v2 >> 32) == want);
                g3 = g3 || ((unsigned)(v3 >> 32) == want);
                if (g0 && g1 && g2 && g3) break;
                if (--budget <= 0) break;                // hang-proof: bail, wrong-but-finite
                __builtin_amdgcn_s_sleep(1);             // backoff: reduce LLC atomic pressure
            }
            float4 hv;
            hv.x = __uint_as_float((unsigned)v0);
            hv.y = __uint_as_float((unsigned)v1);
            hv.z = __uint_as_float((unsigned)v2);
            hv.w = __uint_as_float((unsigned)v3);
            *(float4*)&hbuf[tid * 4] = hv;
        }
        __syncthreads();
        if (kc == 0) { xpc[0] = xpn[0]; xpc[1] = xpn[1]; xpc[2] = xpn[2]; xpc[3] = xpn[3]; }
    }
}

// ============================================================================
// Kernel 3: feats[t][n] = dot(hist[t], w_tag[n]) + b_tag[n]
// ============================================================================
__global__ __launch_bounds__(256)
void feats_kernel(const float* __restrict__ hist,
                  const float* __restrict__ w_tag,
                  const float* __restrict__ b_tag,
                  float* __restrict__ feats)
{
    const int t = blockIdx.x;
    const int tid = threadIdx.x;
    const float* __restrict__ hrow = hist + (size_t)t * 2048 + tid * 8;
    const float4 ha = *(const float4*)&hrow[0];
    const float4 hb = *(const float4*)&hrow[4];
    float p[4];
    #pragma unroll
    for (int n = 0; n < 4; ++n) {
        const float* __restrict__ wr = w_tag + n * 2048 + tid * 8;
        const float4 wa = *(const float4*)&wr[0];
        const float4 wb = *(const float4*)&wr[4];
        p[n] = ha.x*wa.x + ha.y*wa.y + ha.z*wa.z + ha.w*wa.w
             + hb.x*wb.x + hb.y*wb.y + hb.z*wb.z + hb.w*wb.w;
    }
    #pragma unroll
    for (int m = 32; m >= 1; m >>= 1) {
        #pragma unroll
        for (int n = 0; n < 4; ++n) p[n] += __shfl_down(p[n], m);
    }
    __shared__ float red[4][4];
    const int wv = tid >> 6;
    if ((tid & 63) == 0) {
        #pragma unroll
        for (int n = 0; n < 4; ++n) red[n][wv] = p[n];
    }
    __syncthreads();
    if (tid < 4)
        feats[(size_t)t * 4 + tid] = red[tid][0] + red[tid][1] + red[tid][2] + red[tid][3] + b_tag[tid];
}

// ============================================================================
// Kernel 4: Viterbi v2.
// Forward DP: thread 0, bit-exact serial arithmetic, but fsh batch-loaded 8
// rows at a time into registers -> LDS latency off the dependent chain.
// Backtrace: parallel suffix scan of backpointer MAPS (u32-packed 4-maps,
// integer composition = exactly associative -> path bit-identical to serial):
// 256 threads x 16-step chunks; serial 256-chunk aggregate on thread 0.
// ============================================================================
__global__ __launch_bounds__(256)
void viterbi_kernel(const float* __restrict__ feats,
                    const float* __restrict__ trans,
                    float* __restrict__ out)
{
    __shared__ float fsh[T_LEN * 4];   // 64 KB
    __shared__ unsigned bp[T_LEN];     // 16 KB
    __shared__ unsigned lmap[256];
    __shared__ unsigned smap[256];
    __shared__ int bestsh;
    const int tid = threadIdx.x;
    for (int i = tid; i < T_LEN; i += 256)
        *(float4*)&fsh[i * 4] = *(const float4*)&feats[(size_t)i * 4];
    __syncthreads();

    if (tid == 0) {
        float tr[16];
        #pragma unroll
        for (int i = 0; i < 16; ++i) tr[i] = trans[i];
        float fv[4] = {NEGV, NEGV, NEGV, NEGV};
        fv[START_TAG] = 0.0f;
        for (int t0 = 0; t0 < T_LEN; t0 += 8) {
            float4 f8[8];
            #pragma unroll
            for (int j = 0; j < 8; ++j) f8[j] = *(const float4*)&fsh[(t0 + j) * 4];
            #pragma unroll
            for (int j = 0; j < 8; ++j) {
                const float ft[4] = {f8[j].x, f8[j].y, f8[j].z, f8[j].w};
                float nf[4]; unsigned pb = 0;
                #pragma unroll
                for (int n = 0; n < 4; ++n) {
                    float m = fv[0] + tr[n * 4 + 0]; int bsel = 0;
                    #pragma unroll
                    for (int p = 1; p < 4; ++p) {
                        const float s = fv[p] + tr[n * 4 + p];
                        if (s > m) { m = s; bsel = p; }
                    }
                    nf[n] = m + ft[n];
                    pb |= (unsigned)bsel << (8 * n);
                }
                bp[t0 + j] = pb;
                fv[0] = nf[0]; fv[1] = nf[1]; fv[2] = nf[2]; fv[3] = nf[3];
            }
        }
        float bm = fv[0] + tr[STOP_TAG * 4 + 0]; int best = 0;
        #pragma unroll
        for (int p = 1; p < 4; ++p) {
            const float s = fv[p] + tr[STOP_TAG * 4 + p];
            if (s > bm) { bm = s; best = p; }
        }
        out[0] = bm;
        bestsh = best;
    }
    __syncthreads();

    // ---- parallel backtrace: path[t] = (bp[t+1] o ... o bp[T-1])(best) ----
    const int c0 = tid * 16;
    // chunk map L = bp[c0] o bp[c0+1] o ... o bp[c0+15]  (build from the right)
    unsigned L = bp[c0 + 15];
    #pragma unroll
    for (int j = 14; j >= 0; --j) L = compose4(bp[c0 + j], L);
    lmap[tid] = L;
    __syncthreads();
    if (tid == 0) {
        unsigned acc = 0x03020100u;              // identity map
        for (int i = 255; i >= 0; --i) { smap[i] = acc; acc = compose4(lmap[i], acc); }
    }
    __syncthreads();
    // carry = S_{c0+16} (suffix of chunks after this one); walk chunk downward
    unsigned carry = smap[tid];
    const int best = bestsh;
    for (int t = c0 + 15; t >= c0; --t) {
        out[1 + t] = (float)((carry >> (8 * best)) & 3u);   // path[t] = S_{t+1}(best)
        carry = compose4(bp[t], carry);                      // S_t = bp[t] o S_{t+1}
    }
}

// ============================================================================
extern "C" void kernel_launch(void* const* d_in, const int* in_sizes, int n_in,
                              void* d_out, int out_size, void* d_ws, size_t ws_size,
                              hipStream_t stream) {
    const float* x      = (const float*)d_in[0];
    const float* h0     = (const float*)d_in[1];
    const float* c0     = (const float*)d_in[2];
    const float* w_ih_f = (const float*)d_in[3];
    const float* w_hh_f = (const float*)d_in[4];
    const float* b_ih_f = (const float*)d_in[5];
    const float* b_hh_f = (const float*)d_in[6];
    const float* w_ih_b = (const float*)d_in[7];
    const float* w_hh_b = (const float*)d_in[8];
    const float* b_ih_b = (const float*)d_in[9];
    const float* b_hh_b = (const float*)d_in[10];
    const float* w_tag  = (const float*)d_in[11];
    const float* b_tag  = (const float*)d_in[12];
    const float* trans  = (const float*)d_in[13];
    float* out = (float*)d_out;

    if (ws_size < WS_NEED) return;   // signature: output stays poisoned

    char* ws = (char*)d_ws;
    float* xp    = (float*)(ws + XP_OFF);
    float* hist  = (float*)(ws + HIST_OFF);
    float* feats = (float*)(ws + FEATS_OFF);
    unsigned long long* slots = (unsigned long long*)(ws + SLOTS_OFF);
    unsigned short* xb  = (unsigned short*)(ws + XB_OFF);
    unsigned short* wbf = (unsigned short*)(ws + WBF_OFF);
    unsigned short* wbb = (unsigned short*)(ws + WBB_OFF);

    hipMemsetAsync(slots, 0, SLOTS_BYTES, stream);

    // fp32 -> bf16 staging (x, w_ih_f, w_ih_b); each 4096x1024 elems -> n4 = 1M
    const int n4 = (T_LEN * FDIM) / 4;
    conv_bf16<<<1024, 256, 0, stream>>>(x,      xb,  n4);
    conv_bf16<<<1024, 256, 0, stream>>>(w_ih_f, wbf, n4);
    conv_bf16<<<1024, 256, 0, stream>>>(w_ih_b, wbb, n4);

    // bf16 MFMA input GEMM (reads xb/wbf/wbb from the hist region, writes xp)
    xp_gemm_mfma<<<dim3(64, 64, 2), 64, 0, stream>>>(
        xb, wbf, wbb, b_ih_f, b_hh_f, b_ih_b, b_hh_b, xp);

    // scan overwrites the hist region only after the gemm has consumed xb/wb*
    void* ka[] = { (void*)&xp, (void*)&h0, (void*)&c0, (void*)&w_hh_f, (void*)&w_hh_b,
                   (void*)&hist, (void*)&slots };
    hipLaunchCooperativeKernel((void*)lstm_scan, dim3(256), dim3(256), ka, 0, stream);

    feats_kernel<<<T_LEN, 256, 0, stream>>>(hist, w_tag, b_tag, feats);
    viterbi_kernel<<<1, 256, 0, stream>>>(feats, trans, out);
}

// Round 11
// 13797.484 us; speedup vs baseline: 1.3655x; 1.0153x over previous
//
#include <hip/hip_runtime.h>
#include <cstddef>
#include <cstdint>

#define T_LEN 4096
#define FDIM  1024
#define H2DIM 1024
#define GDIM  4096   // 4*H2

#define NEGV (-10000.0f)
#define START_TAG 2
#define STOP_TAG 3

// ---- workspace layout (bytes) ----
#define XP_OFF      ((size_t)0)
#define XP_BYTES    ((size_t)2 * T_LEN * GDIM * 4)          // 134,217,728
#define HIST_OFF    (XP_OFF + XP_BYTES)
#define HIST_BYTES  ((size_t)T_LEN * 2048 * 4)              // 33,554,432
#define FEATS_OFF   (HIST_OFF + HIST_BYTES)
#define FEATS_BYTES ((size_t)T_LEN * 4 * 4)
#define SLOTS_OFF   (FEATS_OFF + FEATS_BYTES)
#define SLOTS_BYTES ((size_t)2 * 2 * 1024 * 8)              // parity x dir x unit, u64
#define WS_NEED     (SLOTS_OFF + SLOTS_BYTES)

// bf16 staging buffers live INSIDE the hist region (dead until the scan runs;
// the gemm finishes reading them before lstm_scan overwrites hist).
#define XB_OFF      (HIST_OFF)                               // 8 MB
#define WBF_OFF     (HIST_OFF + (size_t)8  * 1024 * 1024)    // 8 MB
#define WBB_OFF     (HIST_OFF + (size_t)16 * 1024 * 1024)    // 8 MB

__device__ __forceinline__ float sigm(float x) { return 1.0f / (1.0f + expf(-x)); }

__device__ __forceinline__ unsigned short f2bf(float f) {
    unsigned u = __float_as_uint(f);
    return (unsigned short)((u + 0x7FFFu + ((u >> 16) & 1u)) >> 16);   // RNE
}

// compose two 4-element tag maps packed as u32 (byte c = map(c), values 0..3)
__device__ __forceinline__ unsigned compose4(unsigned A, unsigned B) {
    unsigned r = 0;
    #pragma unroll
    for (int c = 0; c < 4; ++c) {
        const unsigned b = (B >> (8 * c)) & 3u;
        const unsigned a = (A >> (8 * b)) & 3u;
        r |= a << (8 * c);
    }
    return r;
}

typedef short  bf16x8 __attribute__((ext_vector_type(8)));
typedef float  f32x4  __attribute__((ext_vector_type(4)));

// ============================================================================
// Kernel 0: fp32 -> bf16 (RNE), vectorized grid-stride
// ============================================================================
__global__ __launch_bounds__(256)
void conv_bf16(const float* __restrict__ src, unsigned short* __restrict__ dst, int n4)
{
    int i = blockIdx.x * 256 + threadIdx.x;
    const int stride = gridDim.x * 256;
    for (; i < n4; i += stride) {
        const float4 v = ((const float4*)src)[i];
        ushort4 o;
        o.x = f2bf(v.x); o.y = f2bf(v.y); o.z = f2bf(v.z); o.w = f2bf(v.w);
        ((ushort4*)dst)[i] = o;
    }
}

// ============================================================================
// Kernel 1: bf16 MFMA input GEMM, LDS-TILED (v2).
// xp[dir][s][j] = dot(x[row(s)], w_ih_dir[j]) + b_ih[j] + b_hh[j], fp32 out.
// 128x128 tile, BK=32, 256 threads = 4 waves in 2x2 grid of 64x64 quadrants.
// A/B staged reg->LDS [128][40] bf16 (pad 8 -> fragment reads 2 lanes/bank,
// free). Fragment/MFMA/store index math identical to the R9-verified kernel;
// only the fragment source moved to LDS. Global traffic 2GB -> 1GB.
// XCD-swizzled tile grid: swz=(bid&7)*128+(bid>>3), 1024%8==0 -> bijective.
// ============================================================================
__global__ __launch_bounds__(256)
void xp_gemm_mfma(const unsigned short* __restrict__ xb,
                  const unsigned short* __restrict__ wb_f,
                  const unsigned short* __restrict__ wb_b,
                  const float* __restrict__ bi_f, const float* __restrict__ bh_f,
                  const float* __restrict__ bi_b, const float* __restrict__ bh_b,
                  float* __restrict__ xp)
{
    __shared__ unsigned short As[128][40];   // 10,240 B
    __shared__ unsigned short Bs[128][40];   // 10,240 B

    const int tid  = threadIdx.x;
    const int lane = tid & 63;
    const int wv   = tid >> 6;           // wave 0..3
    const int wr   = (wv >> 1) * 64;     // quadrant row offset
    const int wc   = (wv & 1) * 64;      // quadrant col offset
    const int dir  = blockIdx.y;

    // XCD swizzle over the 1024 tile-blocks (round-robin dispatch -> each XCD
    // gets 128 consecutive swz = 4 t-rows x all 32 j-tiles -> A reuse in L2)
    const int bid = blockIdx.x;
    const int swz = (bid & 7) * 128 + (bid >> 3);
    const int t0  = (swz >> 5) * 128;
    const int j0  = (swz & 31) * 128;

    const unsigned short* __restrict__ wb = dir ? wb_b : wb_f;
    const float* __restrict__ bi = dir ? bi_b : bi_f;
    const float* __restrict__ bh = dir ? bh_b : bh_f;

    const int r  = lane & 15;
    const int kg = lane >> 4;            // k-group 0..3

    // staging coords: thread -> rows {srow, srow+64}, k-span skp..skp+7
    const int srow = tid >> 2;           // 0..63
    const int skp  = (tid & 3) * 8;      // 0,8,16,24

    // global row addresses for A staging (scan-order row reversal for dir=1)
    const int tgA0 = t0 + srow;
    const int tgA1 = t0 + srow + 64;
    const size_t arow0 = (size_t)(dir ? (T_LEN - 1 - tgA0) : tgA0) * FDIM;
    const size_t arow1 = (size_t)(dir ? (T_LEN - 1 - tgA1) : tgA1) * FDIM;
    const size_t brow0 = (size_t)(j0 + srow) * FDIM;
    const size_t brow1 = (size_t)(j0 + srow + 64) * FDIM;

    f32x4 acc[4][4];
    #pragma unroll
    for (int sm = 0; sm < 4; ++sm)
        #pragma unroll
        for (int sn = 0; sn < 4; ++sn)
            acc[sm][sn] = (f32x4){0.f, 0.f, 0.f, 0.f};

    for (int kb = 0; kb < FDIM; kb += 32) {
        __syncthreads();   // previous iter's fragment reads complete
        *(bf16x8*)&As[srow     ][skp] = *(const bf16x8*)&xb[arow0 + kb + skp];
        *(bf16x8*)&As[srow + 64][skp] = *(const bf16x8*)&xb[arow1 + kb + skp];
        *(bf16x8*)&Bs[srow     ][skp] = *(const bf16x8*)&wb[brow0 + kb + skp];
        *(bf16x8*)&Bs[srow + 64][skp] = *(const bf16x8*)&wb[brow1 + kb + skp];
        __syncthreads();   // tiles staged

        bf16x8 a[4], b[4];
        #pragma unroll
        for (int s = 0; s < 4; ++s) {
            a[s] = *(const bf16x8*)&As[wr + s * 16 + r][kg * 8];
            b[s] = *(const bf16x8*)&Bs[wc + s * 16 + r][kg * 8];
        }
        #pragma unroll
        for (int sm = 0; sm < 4; ++sm)
            #pragma unroll
            for (int sn = 0; sn < 4; ++sn)
                acc[sm][sn] = __builtin_amdgcn_mfma_f32_16x16x32_bf16(
                                  a[sm], b[sn], acc[sm][sn], 0, 0, 0);
    }

    float* __restrict__ xpd = xp + (size_t)dir * T_LEN * GDIM;
    #pragma unroll
    for (int sn = 0; sn < 4; ++sn) {
        const int col  = j0 + wc + sn * 16 + r;
        const float bv = bi[col] + bh[col];
        #pragma unroll
        for (int sm = 0; sm < 4; ++sm) {
            #pragma unroll
            for (int j = 0; j < 4; ++j) {
                const int row = t0 + wr + sm * 16 + kg * 4 + j;
                xpd[(size_t)row * GDIM + col] = acc[sm][sn][j] + bv;
            }
        }
    }
}

// ============================================================================
// Kernel 2: cooperative persistent bidirectional LSTM scan (R10, unchanged).
// dir = b&1 XCD swizzle: each direction's 128 communicating blocks stay on
// 4 XCDs -> slot traffic XCD-local (FETCH 772->554 MB, -0.38 ms measured).
// ============================================================================
__global__ __launch_bounds__(256, 1)
void lstm_scan(const float* __restrict__ xp,
               const float* __restrict__ h0,
               const float* __restrict__ c0,
               const float* __restrict__ whh_f,
               const float* __restrict__ whh_b,
               float* __restrict__ hist,
               unsigned long long* __restrict__ slots)
{
    __shared__ float wsl[32][1024];   // 131072 B
    __shared__ float hbuf[1024];      //   4096 B
    __shared__ float gsh[32];

    const int tid = threadIdx.x;
    const int b   = blockIdx.x;
    const int dir = b & 1;            // XCD swizzle: fwd on even, bwd on odd
    const int bi  = b >> 1;
    const int u0  = bi * 8;
    const int rg  = tid >> 5;   // 0..7  (row group: 4 rows)
    const int kc  = tid & 31;   // 0..31 (k chunk)
    const int lrb = rg * 4;

    const float* __restrict__ whh = dir ? whh_b : whh_f;
    const size_t xpbase = (size_t)dir * T_LEN * GDIM;

    for (int lr = 0; lr < 32; ++lr) {
        const int grow = ((lr >> 3) << 10) + u0 + (lr & 7);
        *(float4*)&wsl[lr][tid * 4] = *(const float4*)&whh[(size_t)grow * H2DIM + tid * 4];
    }
    *(float4*)&hbuf[tid * 4] = *(const float4*)&h0[dir * H2DIM + tid * 4];
    float creg = 0.f;
    if (tid < 8) creg = c0[dir * H2DIM + u0 + tid];

    int grows[4];
    #pragma unroll
    for (int j = 0; j < 4; ++j) {
        const int lr = lrb + j;
        grows[j] = ((lr >> 3) << 10) + u0 + (lr & 7);
    }
    float xpc[4] = {0.f, 0.f, 0.f, 0.f};
    if (kc == 0) {
        #pragma unroll
        for (int j = 0; j < 4; ++j) xpc[j] = xp[xpbase + grows[j]];
    }
    __syncthreads();

    int budget = 4000000;

    for (int t = 0; t < T_LEN; ++t) {
        float xpn[4] = {0.f, 0.f, 0.f, 0.f};
        const int tnx = (t + 1 < T_LEN) ? (t + 1) : t;
        if (kc == 0) {
            #pragma unroll
            for (int j = 0; j < 4; ++j) xpn[j] = xp[xpbase + (size_t)tnx * GDIM + grows[j]];
        }

        float p0 = 0.f, p1 = 0.f, p2 = 0.f, p3 = 0.f;
        #pragma unroll
        for (int s = 0; s < 8; ++s) {
            const int ko = s * 128 + kc * 4;
            const float4 hv = *(const float4*)&hbuf[ko];
            const float4 w0 = *(const float4*)&wsl[lrb + 0][ko];
            const float4 w1 = *(const float4*)&wsl[lrb + 1][ko];
            const float4 w2 = *(const float4*)&wsl[lrb + 2][ko];
            const float4 w3 = *(const float4*)&wsl[lrb + 3][ko];
            p0 += w0.x*hv.x + w0.y*hv.y + w0.z*hv.z + w0.w*hv.w;
            p1 += w1.x*hv.x + w1.y*hv.y + w1.z*hv.z + w1.w*hv.w;
            p2 += w2.x*hv.x + w2.y*hv.y + w2.z*hv.z + w2.w*hv.w;
            p3 += w3.x*hv.x + w3.y*hv.y + w3.z*hv.z + w3.w*hv.w;
        }
        #pragma unroll
        for (int m = 16; m >= 1; m >>= 1) {
            p0 += __shfl_xor(p0, m);
            p1 += __shfl_xor(p1, m);
            p2 += __shfl_xor(p2, m);
            p3 += __shfl_xor(p3, m);
        }
        if (kc == 0) {
            gsh[lrb + 0] = p0 + xpc[0];
            gsh[lrb + 1] = p1 + xpc[1];
            gsh[lrb + 2] = p2 + xpc[2];
            gsh[lrb + 3] = p3 + xpc[3];
        }
        __syncthreads();

        if (tid < 8) {
            const float gi = gsh[tid];
            const float gf = gsh[8 + tid];
            const float gg = gsh[16 + tid];
            const float go = gsh[24 + tid];
            const float c  = sigm(gf) * creg + sigm(gi) * tanhf(gg);
            const float h  = sigm(go) * tanhf(c);
            creg = c;
            const int tg = dir ? (T_LEN - 1 - t) : t;
            hist[(size_t)tg * 2048 + dir * H2DIM + u0 + tid] = h;
            const unsigned long long pack =
                ((unsigned long long)(unsigned)(t + 1) << 32) |
                (unsigned long long)__float_as_uint(h);
            __hip_atomic_store(&slots[((size_t)((t + 1) & 1) * 2 + dir) * H2DIM + u0 + tid],
                               pack, __ATOMIC_RELAXED, __HIP_MEMORY_SCOPE_AGENT);
        }

        if (t + 1 < T_LEN) {
            const unsigned want = (unsigned)(t + 1);
            unsigned long long* sb = &slots[((size_t)((t + 1) & 1) * 2 + dir) * H2DIM + tid * 4];
            unsigned long long v0 = 0, v1 = 0, v2 = 0, v3 = 0;
            bool g0 = false, g1 = false, g2 = false, g3 = false;
            for (;;) {
                if (!g0) v0 = __hip_atomic_load(&sb[0], __ATOMIC_RELAXED, __HIP_MEMORY_SCOPE_AGENT);
                if (!g1) v1 = __hip_atomic_load(&sb[1], __ATOMIC_RELAXED, __HIP_MEMORY_SCOPE_AGENT);
                if (!g2) v2 = __hip_atomic_load(&sb[2], __ATOMIC_RELAXED, __HIP_MEMORY_SCOPE_AGENT);
                if (!g3) v3 = __hip_atomic_load(&sb[3], __ATOMIC_RELAXED, __HIP_MEMORY_SCOPE_AGENT);
                g0 = g0 || ((unsigned)(v0 >> 32) == want);
                g1 = g1 || ((unsigned)(v1 >> 32) == want);
                g2 = g2 || ((unsigned)(v2 >> 32) == want);
                g3 = g3 || ((unsigned)(v3 >> 32) == want);
                if (g0 && g1 && g2 && g3) break;
                if (--budget <= 0) break;
                __builtin_amdgcn_s_sleep(1);
            }
            float4 hv;
            hv.x = __uint_as_float((unsigned)v0);
            hv.y = __uint_as_float((unsigned)v1);
            hv.z = __uint_as_float((unsigned)v2);
            hv.w = __uint_as_float((unsigned)v3);
            *(float4*)&hbuf[tid * 4] = hv;
        }
        __syncthreads();
        if (kc == 0) { xpc[0] = xpn[0]; xpc[1] = xpn[1]; xpc[2] = xpn[2]; xpc[3] = xpn[3]; }
    }
}

// ============================================================================
// Kernel 3: feats[t][n] = dot(hist[t], w_tag[n]) + b_tag[n]
// ============================================================================
__global__ __launch_bounds__(256)
void feats_kernel(const float* __restrict__ hist,
                  const float* __restrict__ w_tag,
                  const float* __restrict__ b_tag,
                  float* __restrict__ feats)
{
    const int t = blockIdx.x;
    const int tid = threadIdx.x;
    const float* __restrict__ hrow = hist + (size_t)t * 2048 + tid * 8;
    const float4 ha = *(const float4*)&hrow[0];
    const float4 hb = *(const float4*)&hrow[4];
    float p[4];
    #pragma unroll
    for (int n = 0; n < 4; ++n) {
        const float* __restrict__ wr = w_tag + n * 2048 + tid * 8;
        const float4 wa = *(const float4*)&wr[0];
        const float4 wb = *(const float4*)&wr[4];
        p[n] = ha.x*wa.x + ha.y*wa.y + ha.z*wa.z + ha.w*wa.w
             + hb.x*wb.x + hb.y*wb.y + hb.z*wb.z + hb.w*wb.w;
    }
    #pragma unroll
    for (int m = 32; m >= 1; m >>= 1) {
        #pragma unroll
        for (int n = 0; n < 4; ++n) p[n] += __shfl_down(p[n], m);
    }
    __shared__ float red[4][4];
    const int wv = tid >> 6;
    if ((tid & 63) == 0) {
        #pragma unroll
        for (int n = 0; n < 4; ++n) red[n][wv] = p[n];
    }
    __syncthreads();
    if (tid < 4)
        feats[(size_t)t * 4 + tid] = red[tid][0] + red[tid][1] + red[tid][2] + red[tid][3] + b_tag[tid];
}

// ============================================================================
// Kernel 4: Viterbi v2 (R10, unchanged; absmax=0 verified).
// ============================================================================
__global__ __launch_bounds__(256)
void viterbi_kernel(const float* __restrict__ feats,
                    const float* __restrict__ trans,
                    float* __restrict__ out)
{
    __shared__ float fsh[T_LEN * 4];   // 64 KB
    __shared__ unsigned bp[T_LEN];     // 16 KB
    __shared__ unsigned lmap[256];
    __shared__ unsigned smap[256];
    __shared__ int bestsh;
    const int tid = threadIdx.x;
    for (int i = tid; i < T_LEN; i += 256)
        *(float4*)&fsh[i * 4] = *(const float4*)&feats[(size_t)i * 4];
    __syncthreads();

    if (tid == 0) {
        float tr[16];
        #pragma unroll
        for (int i = 0; i < 16; ++i) tr[i] = trans[i];
        float fv[4] = {NEGV, NEGV, NEGV, NEGV};
        fv[START_TAG] = 0.0f;
        for (int t0 = 0; t0 < T_LEN; t0 += 8) {
            float4 f8[8];
            #pragma unroll
            for (int j = 0; j < 8; ++j) f8[j] = *(const float4*)&fsh[(t0 + j) * 4];
            #pragma unroll
            for (int j = 0; j < 8; ++j) {
                const float ft[4] = {f8[j].x, f8[j].y, f8[j].z, f8[j].w};
                float nf[4]; unsigned pb = 0;
                #pragma unroll
                for (int n = 0; n < 4; ++n) {
                    float m = fv[0] + tr[n * 4 + 0]; int bsel = 0;
                    #pragma unroll
                    for (int p = 1; p < 4; ++p) {
                        const float s = fv[p] + tr[n * 4 + p];
                        if (s > m) { m = s; bsel = p; }
                    }
                    nf[n] = m + ft[n];
                    pb |= (unsigned)bsel << (8 * n);
                }
                bp[t0 + j] = pb;
                fv[0] = nf[0]; fv[1] = nf[1]; fv[2] = nf[2]; fv[3] = nf[3];
            }
        }
        float bm = fv[0] + tr[STOP_TAG * 4 + 0]; int best = 0;
        #pragma unroll
        for (int p = 1; p < 4; ++p) {
            const float s = fv[p] + tr[STOP_TAG * 4 + p];
            if (s > bm) { bm = s; best = p; }
        }
        out[0] = bm;
        bestsh = best;
    }
    __syncthreads();

    const int c0 = tid * 16;
    unsigned L = bp[c0 + 15];
    #pragma unroll
    for (int j = 14; j >= 0; --j) L = compose4(bp[c0 + j], L);
    lmap[tid] = L;
    __syncthreads();
    if (tid == 0) {
        unsigned acc = 0x03020100u;              // identity map
        for (int i = 255; i >= 0; --i) { smap[i] = acc; acc = compose4(lmap[i], acc); }
    }
    __syncthreads();
    unsigned carry = smap[tid];
    const int best = bestsh;
    for (int t = c0 + 15; t >= c0; --t) {
        out[1 + t] = (float)((carry >> (8 * best)) & 3u);
        carry = compose4(bp[t], carry);
    }
}

// ============================================================================
extern "C" void kernel_launch(void* const* d_in, const int* in_sizes, int n_in,
                              void* d_out, int out_size, void* d_ws, size_t ws_size,
                              hipStream_t stream) {
    const float* x      = (const float*)d_in[0];
    const float* h0     = (const float*)d_in[1];
    const float* c0     = (const float*)d_in[2];
    const float* w_ih_f = (const float*)d_in[3];
    const float* w_hh_f = (const float*)d_in[4];
    const float* b_ih_f = (const float*)d_in[5];
    const float* b_hh_f = (const float*)d_in[6];
    const float* w_ih_b = (const float*)d_in[7];
    const float* w_hh_b = (const float*)d_in[8];
    const float* b_ih_b = (const float*)d_in[9];
    const float* b_hh_b = (const float*)d_in[10];
    const float* w_tag  = (const float*)d_in[11];
    const float* b_tag  = (const float*)d_in[12];
    const float* trans  = (const float*)d_in[13];
    float* out = (float*)d_out;

    if (ws_size < WS_NEED) return;   // signature: output stays poisoned

    char* ws = (char*)d_ws;
    float* xp    = (float*)(ws + XP_OFF);
    float* hist  = (float*)(ws + HIST_OFF);
    float* feats = (float*)(ws + FEATS_OFF);
    unsigned long long* slots = (unsigned long long*)(ws + SLOTS_OFF);
    unsigned short* xb  = (unsigned short*)(ws + XB_OFF);
    unsigned short* wbf = (unsigned short*)(ws + WBF_OFF);
    unsigned short* wbb = (unsigned short*)(ws + WBB_OFF);

    hipMemsetAsync(slots, 0, SLOTS_BYTES, stream);

    // fp32 -> bf16 staging (x, w_ih_f, w_ih_b); each 4096x1024 elems -> n4 = 1M
    const int n4 = (T_LEN * FDIM) / 4;
    conv_bf16<<<1024, 256, 0, stream>>>(x,      xb,  n4);
    conv_bf16<<<1024, 256, 0, stream>>>(w_ih_f, wbf, n4);
    conv_bf16<<<1024, 256, 0, stream>>>(w_ih_b, wbb, n4);

    // LDS-tiled bf16 MFMA input GEMM
    xp_gemm_mfma<<<dim3(1024, 2), 256, 0, stream>>>(
        xb, wbf, wbb, b_ih_f, b_hh_f, b_ih_b, b_hh_b, xp);

    // scan overwrites the hist region only after the gemm has consumed xb/wb*
    void* ka[] = { (void*)&xp, (void*)&h0, (void*)&c0, (void*)&w_hh_f, (void*)&w_hh_b,
                   (void*)&hist, (void*)&slots };
    hipLaunchCooperativeKernel((void*)lstm_scan, dim3(256), dim3(256), ka, 0, stream);

    feats_kernel<<<T_LEN, 256, 0, stream>>>(hist, w_tag, b_tag, feats);
    viterbi_kernel<<<1, 256, 0, stream>>>(feats, trans, out);
}